// Round 7
// baseline (309.602 us; speedup 1.0000x reference)
//
#include <hip/hip_runtime.h>

#define B_N 4096
#define KE 64
#define R_N 16

typedef unsigned short u16;
typedef __attribute__((ext_vector_type(4))) float f4;
typedef __attribute__((ext_vector_type(4))) float f32x4;
typedef __attribute__((ext_vector_type(8))) short bf16x8;

__device__ __forceinline__ float b2f(u16 u) {
  union { unsigned int i; float f; } z; z.i = ((unsigned int)u) << 16; return z.f;
}
__device__ __forceinline__ u16 f2b(float f) {
  union { float f; unsigned int i; } z; z.f = f;
  unsigned int r = (z.i + 0x7FFFu + ((z.i >> 16) & 1u)) >> 16;
  return (u16)r;
}

// ---------------------------------------------------------------------------
// stage a row-major bf16 tile [ROWS][8<<LOG2SLOTS k-cols] into LDS via
// global_load_lds(16B), with row-XOR slot swizzle applied on the GLOBAL source
// (LDS dest stays lane-linear; the matching XOR is applied on ds_read).
// 256 threads assumed.
// ---------------------------------------------------------------------------
template<int LOG2SLOTS, int NISS>
__device__ __forceinline__ void stage_tile(const u16* gbase, size_t gstride,
                                           u16* lds, int t) {
#pragma unroll
  for (int s = 0; s < NISS; ++s) {
    const int lin = s * 256 + t;
    const int r = lin >> LOG2SLOTS;
    const int p = lin & ((1 << LOG2SLOTS) - 1);
    const int lsl = p ^ (r & 7);
    const u16* src = gbase + (size_t)r * gstride + (lsl << 3);
    __builtin_amdgcn_global_load_lds(
        (const __attribute__((address_space(1))) void*)src,
        (__attribute__((address_space(3))) void*)(lds + (size_t)lin * 8), 16, 0, 0);
  }
}

// ---------------------------------------------------------------------------
// prep 1: WcatT[(l*128+e)][(r*128+d)] = bf16(W_rel[l][r][d][e])  (transpose d<->e)
// grid (32 = l*16+r, 8 = 16-col chunk), block 256
// ---------------------------------------------------------------------------
__global__ __launch_bounds__(256) void k_prep_wcat(const float* __restrict__ W_rel,
                                                   u16* __restrict__ WcatT) {
  __shared__ __align__(16) u16 T[16][136];  // [e_local][d], pad 136 (17*16B rows)
  const int lr = blockIdx.x;   // l*16 + r
  const int c = blockIdx.y;    // e-chunk
  const int t = threadIdx.x;
  const float* src = W_rel + (size_t)lr * 128 * 128;  // [d][e]
  const int d = t >> 1, h = t & 1;
#pragma unroll
  for (int hh = 0; hh < 2; ++hh) {
    const f4 v = *(const f4*)(src + (size_t)d * 128 + c * 16 + h * 8 + hh * 4);
#pragma unroll
    for (int j = 0; j < 4; ++j) T[h * 8 + hh * 4 + j][d] = f2b(v[j]);
  }
  __syncthreads();
  const int l = lr >> 4, r = lr & 15;
  const int e_l = t >> 4, d0 = (t & 15) * 8;
  bf16x8 w;
#pragma unroll
  for (int i = 0; i < 8; ++i) w[i] = (short)T[e_l][d0 + i];
  *(bf16x8*)(WcatT + (size_t)(l * 128 + c * 16 + e_l) * 2048 + r * 128 + d0) = w;
}

// ---------------------------------------------------------------------------
// prep 2: straight fp32->bf16 casts (layouts already [N][K])
// resWT (32768) | in_wT (49152) | out_wT (16384); grid 384, block 256
// ---------------------------------------------------------------------------
__global__ __launch_bounds__(256) void k_prep_cast(const float* __restrict__ res_W,
                                                   const float* __restrict__ in_w,
                                                   const float* __restrict__ out_w,
                                                   u16* __restrict__ resWT,
                                                   u16* __restrict__ in_wT,
                                                   u16* __restrict__ out_wT) {
  const int i = blockIdx.x * 256 + threadIdx.x;
  if (i < 32768) resWT[i] = f2b(res_W[i]);
  else if (i < 81920) in_wT[i - 32768] = f2b(in_w[i - 32768]);
  else out_wT[i - 81920] = f2b(out_w[i - 81920]);
}

// ---------------------------------------------------------------------------
// gather v2: agg[b][r*128+d] = sum_k (rel==r) w_k*E[ent_k][d] (bf16), x0 = E[didx] bf16
// grid 4096, block 256: thread (k = t>>2 edge, q = t&3 quarter-strip of 32 floats).
// ALL loads independent (8 f4 in flight per lane); scatter via LDS atomicAdd
// (ds_add_f32) into one 8 KB slab; f4 sequence staggered by (i+k)&7 to spread
// banks (64-way -> ~8-way). 8 KB LDS + ~60 VGPR -> 8 blocks/CU (100% occ).
// ---------------------------------------------------------------------------
__global__ __launch_bounds__(256) void k_gather(
    const int* __restrict__ didx, const int* __restrict__ adj_e,
    const int* __restrict__ adj_r, const float* __restrict__ ew,
    const float* __restrict__ E, u16* __restrict__ agg, u16* __restrict__ x0) {
  __shared__ __align__(16) float sa[R_N][128];  // 8 KB
  const int b = blockIdx.x;
  const int t = threadIdx.x;
  float* flat = &sa[0][0];
#pragma unroll
  for (int i = 0; i < 8; ++i) flat[t + 256 * i] = 0.f;
  __syncthreads();
  const int k = t >> 2, q = t & 3;
  const int e = adj_e[b * KE + k];
  const int r = adj_r[b * KE + k];
  const float wk = ew[b * KE + k];
  const float* strip = E + (size_t)e * 128 + q * 32;
  f4 v[8];
#pragma unroll
  for (int i = 0; i < 8; ++i) v[i] = *(const f4*)(strip + (((i + k) & 7) << 2));
  float* dst = &sa[r][q * 32];
#pragma unroll
  for (int i = 0; i < 8; ++i) {
    const int p0 = ((i + k) & 7) << 2;
#pragma unroll
    for (int j = 0; j < 4; ++j) atomicAdd(&dst[p0 + j], wk * v[i][j]);
  }
  __syncthreads();
  // pack 2048 bf16: thread t owns floats [t*8, t*8+8)
  {
    const int o0 = t * 8;
    bf16x8 w;
#pragma unroll
    for (int i = 0; i < 8; ++i) w[i] = (short)f2b(flat[o0 + i]);
    *(bf16x8*)(agg + (size_t)b * 2048 + o0) = w;
  }
  if (t < 16) {
    const float* src = E + (size_t)didx[b] * 128 + t * 8;
    bf16x8 w;
#pragma unroll
    for (int i = 0; i < 8; ++i) w[i] = (short)f2b(src[i]);
    *(bf16x8*)(x0 + (size_t)b * 128 + t * 8) = w;
  }
}

// ---------------------------------------------------------------------------
// msgs GEMM: Cp[sp][4096][256] = A[4096][2048]bf16 x WcatT^T  (split-K=4)
// grid (32, 2, 4), block 256 (4 waves, 64x64 wave tiles), BK=64 double-buffered
// ---------------------------------------------------------------------------
__global__ __launch_bounds__(256) void k_msgs(const u16* __restrict__ agg,
                                              const u16* __restrict__ WcatT,
                                              float* __restrict__ Cp) {
  __shared__ __align__(16) u16 As[2][128 * 64];
  __shared__ __align__(16) u16 Bs[2][128 * 64];
  const int t = threadIdx.x;
  const int bm = blockIdx.x, bn = blockIdx.y, sp = blockIdx.z;
  const int w = t >> 6, l = t & 63;
  const int wm = w >> 1, wn = w & 1;
  const int l16 = l & 15, l4 = l >> 4;
  const u16* Abase = agg + (size_t)bm * 128 * 2048 + sp * 512;
  const u16* Bbase = WcatT + (size_t)bn * 128 * 2048 + sp * 512;
  f32x4 acc[4][4] = {};

  stage_tile<3, 4>(Abase, 2048, As[0], t);
  stage_tile<3, 4>(Bbase, 2048, Bs[0], t);
  __syncthreads();
#pragma unroll 1
  for (int c = 0; c < 8; ++c) {
    const int cur = c & 1;
    if (c < 7) {  // issue next-chunk loads BEFORE compute (2-phase template)
      stage_tile<3, 4>(Abase + (c + 1) * 64, 2048, As[cur ^ 1], t);
      stage_tile<3, 4>(Bbase + (c + 1) * 64, 2048, Bs[cur ^ 1], t);
    }
#pragma unroll
    for (int ks = 0; ks < 2; ++ks) {
      bf16x8 a[4], b[4];
#pragma unroll
      for (int mi = 0; mi < 4; ++mi) {
        const int r = wm * 64 + mi * 16 + l16;
        const int phys = ((ks << 2) + l4) ^ (r & 7);
        a[mi] = *(const bf16x8*)&As[cur][r * 64 + phys * 8];
      }
#pragma unroll
      for (int ni = 0; ni < 4; ++ni) {
        const int r = wn * 64 + ni * 16 + l16;
        const int phys = ((ks << 2) + l4) ^ (r & 7);
        b[ni] = *(const bf16x8*)&Bs[cur][r * 64 + phys * 8];
      }
#pragma unroll
      for (int mi = 0; mi < 4; ++mi)
#pragma unroll
        for (int ni = 0; ni < 4; ++ni)
          acc[mi][ni] =
              __builtin_amdgcn_mfma_f32_16x16x32_bf16(a[mi], b[ni], acc[mi][ni], 0, 0, 0);
    }
    __syncthreads();  // drains global_load_lds (vmcnt(0)) + guards LDS reuse
  }
  float* cp = Cp + (size_t)sp * B_N * 256;
#pragma unroll
  for (int mi = 0; mi < 4; ++mi) {
    const int m0 = bm * 128 + wm * 64 + mi * 16 + l4 * 4;
#pragma unroll
    for (int ni = 0; ni < 4; ++ni) {
      const int n = bn * 128 + wn * 64 + ni * 16 + l16;
#pragma unroll
      for (int j = 0; j < 4; ++j) cp[(size_t)(m0 + j) * 256 + n] = acc[mi][ni][j];
    }
  }
}

// ---------------------------------------------------------------------------
// small GEMM (K=128): C = A[M][128]bf16 x BT[N][128]bf16^T + epilogue
// MODE 0: +bias -> bf16 | MODE 1: +bias -> f32 | MODE 2: +bias+x+sum(msgsP)+relu -> bf16
// grid (M/64, N/64), block 256 (4 waves, 32x32 wave tiles)
// ---------------------------------------------------------------------------
template<int MODE>
__global__ __launch_bounds__(256) void k_small(const u16* __restrict__ A,
                                               const u16* __restrict__ BT,
                                               const float* __restrict__ bias,
                                               void* __restrict__ Cout, int ldc,
                                               const float* __restrict__ msgsP,
                                               int mcol0) {
  __shared__ __align__(16) u16 As[64 * 128];
  __shared__ __align__(16) u16 Bs[64 * 128];
  const int t = threadIdx.x;
  const int row0 = blockIdx.x * 64;
  const int n0 = blockIdx.y * 64;
  const int w = t >> 6, l = t & 63;
  const int wm = w >> 1, wn = w & 1;
  const int l16 = l & 15, l4 = l >> 4;
  stage_tile<4, 4>(A + (size_t)row0 * 128, 128, As, t);
  stage_tile<4, 4>(BT + (size_t)n0 * 128, 128, Bs, t);
  __syncthreads();
  f32x4 acc[2][2] = {};
#pragma unroll
  for (int ks = 0; ks < 4; ++ks) {
    bf16x8 a[2], b[2];
#pragma unroll
    for (int mi = 0; mi < 2; ++mi) {
      const int r = wm * 32 + mi * 16 + l16;
      const int phys = ((ks << 2) + l4) ^ (r & 7);
      a[mi] = *(const bf16x8*)&As[r * 128 + phys * 8];
    }
#pragma unroll
    for (int ni = 0; ni < 2; ++ni) {
      const int r = wn * 32 + ni * 16 + l16;
      const int phys = ((ks << 2) + l4) ^ (r & 7);
      b[ni] = *(const bf16x8*)&Bs[r * 128 + phys * 8];
    }
#pragma unroll
    for (int mi = 0; mi < 2; ++mi)
#pragma unroll
      for (int ni = 0; ni < 2; ++ni)
        acc[mi][ni] =
            __builtin_amdgcn_mfma_f32_16x16x32_bf16(a[mi], b[ni], acc[mi][ni], 0, 0, 0);
  }
  const size_t BSZ = (size_t)B_N * 256;
#pragma unroll
  for (int mi = 0; mi < 2; ++mi) {
#pragma unroll
    for (int ni = 0; ni < 2; ++ni) {
      const int n = n0 + wn * 32 + ni * 16 + l16;
#pragma unroll
      for (int j = 0; j < 4; ++j) {
        const int m = row0 + wm * 32 + mi * 16 + l4 * 4 + j;
        float v = acc[mi][ni][j] + bias[n];
        if (MODE == 2) {
          const size_t mo = (size_t)m * 256 + mcol0 + n;
          v += b2f(A[(size_t)m * 128 + n]) + msgsP[mo] + msgsP[BSZ + mo] +
               msgsP[2 * BSZ + mo] + msgsP[3 * BSZ + mo];
          v = fmaxf(v, 0.f);
        }
        if (MODE == 1)
          ((float*)Cout)[(size_t)m * ldc + n] = v;
        else
          ((u16*)Cout)[(size_t)m * ldc + n] = f2b(v);
      }
    }
  }
}

// ---------------------------------------------------------------------------
// attention over L=2 (heads = 32-lane groups), mean folded: om = 0.5*(o0+o1) bf16
// ---------------------------------------------------------------------------
__global__ __launch_bounds__(256) void k_attn(const u16* __restrict__ qkv,
                                              u16* __restrict__ om) {
  const int t = blockIdx.x * 256 + threadIdx.x;
  const int b = t >> 7, d = t & 127;
  const u16* p0 = qkv + (size_t)b * 384;
  const u16* p1 = qkv + (size_t)(B_N + b) * 384;
  const float q0 = b2f(p0[d]), q1 = b2f(p1[d]);
  const float k0 = b2f(p0[128 + d]), k1 = b2f(p1[128 + d]);
  const float v0 = b2f(p0[256 + d]), v1 = b2f(p1[256 + d]);
  float p00 = q0 * k0, p01 = q0 * k1, p10 = q1 * k0, p11 = q1 * k1;
#pragma unroll
  for (int m = 16; m >= 1; m >>= 1) {
    p00 += __shfl_xor(p00, m);
    p01 += __shfl_xor(p01, m);
    p10 += __shfl_xor(p10, m);
    p11 += __shfl_xor(p11, m);
  }
  const float sc = 0.17677669529663687f;  // 1/sqrt(32)
  const float s00 = p00 * sc, s01 = p01 * sc, s10 = p10 * sc, s11 = p11 * sc;
  const float m0 = fmaxf(s00, s01);
  const float e00 = __expf(s00 - m0), e01 = __expf(s01 - m0);
  const float o0 = (e00 * v0 + e01 * v1) / (e00 + e01);
  const float m1 = fmaxf(s10, s11);
  const float e10 = __expf(s10 - m1), e11 = __expf(s11 - m1);
  const float o1 = (e10 * v0 + e11 * v1) / (e10 + e11);
  om[t] = f2b(0.5f * (o0 + o1));
}

// ---------------------------------------------------------------------------
extern "C" void kernel_launch(void* const* d_in, const int* in_sizes, int n_in,
                              void* d_out, int out_size, void* d_ws, size_t ws_size,
                              hipStream_t stream) {
  const int* didx = (const int*)d_in[0];
  const int* adj_e = (const int*)d_in[1];
  const int* adj_r = (const int*)d_in[2];
  const float* ew = (const float*)d_in[3];
  const float* E = (const float*)d_in[4];
  const float* W_rel = (const float*)d_in[5];
  const float* res_W = (const float*)d_in[6];
  const float* res_b = (const float*)d_in[7];
  const float* in_w = (const float*)d_in[8];
  const float* in_b = (const float*)d_in[9];
  const float* out_w = (const float*)d_in[10];
  const float* out_b = (const float*)d_in[11];

  char* ws = (char*)d_ws;
  u16* agg = (u16*)(ws + 0);                     // 16 MB
  u16* WcatT = (u16*)(ws + 16777216);            // 1 MB
  u16* resWT = (u16*)(ws + 17825792);            // 64 KB
  u16* in_wT = (u16*)(ws + 17891328);            // 96 KB
  u16* out_wT = (u16*)(ws + 17989632);           // 32 KB
  u16* x0 = (u16*)(ws + 18022400);               // 1 MB
  u16* xs = (u16*)(ws + 19070976);               // 2 MB  [2][4096][128]
  u16* qkv = (u16*)(ws + 21168128);              // 6 MB  [2][4096][384]
  u16* om = (u16*)(ws + 27459584);               // 1 MB
  float* Cp = (float*)(ws + 28508160);           // 16 MB [4][4096][256]

  k_prep_wcat<<<dim3(32, 8), 256, 0, stream>>>(W_rel, WcatT);
  k_prep_cast<<<384, 256, 0, stream>>>(res_W, in_w, out_w, resWT, in_wT, out_wT);
  k_gather<<<B_N, 256, 0, stream>>>(didx, adj_e, adj_r, ew, E, agg, x0);
  k_msgs<<<dim3(32, 2, 4), 256, 0, stream>>>(agg, WcatT, Cp);

  // layer updates: x1 = relu(x0 + msgs0 + x0*resW0^T + b0); x2 likewise
  k_small<2><<<dim3(64, 2), 256, 0, stream>>>(x0, resWT, res_b, xs, 128, Cp, 0);
  k_small<2><<<dim3(64, 2), 256, 0, stream>>>(xs, resWT + 16384, res_b + 128,
                                              xs + (size_t)B_N * 128, 128, Cp, 128);
  // qkv projection over [x1; x2] (M=8192, N=384)
  k_small<0><<<dim3(128, 6), 256, 0, stream>>>(xs, in_wT, in_b, qkv, 384, nullptr, 0);
  k_attn<<<(B_N * 128) / 256, 256, 0, stream>>>(qkv, om);
  // out projection -> f32 d_out
  k_small<1><<<dim3(64, 2), 256, 0, stream>>>(om, out_wT, out_b, d_out, 128, nullptr, 0);
}